// Round 1
// baseline (1622.182 us; speedup 1.0000x reference)
//
#include <hip/hip_runtime.h>
#include <hip/hip_bf16.h>
#include <math.h>

#define N_NODES 20000
#define N_EDGES 160000
#define D1 512   // layer-1 width: 4 heads * 128
#define D2 64    // layer-2 width: 1 head * 64

// ---------------------------------------------------------------------------
// CSR build (by dst)
// ---------------------------------------------------------------------------
__global__ void hist_kernel(const int* __restrict__ ei, int* __restrict__ deg) {
    int e = blockIdx.x * blockDim.x + threadIdx.x;
    if (e < N_EDGES) atomicAdd(&deg[ei[N_EDGES + e]], 1);
}

__global__ void scan_kernel(const int* __restrict__ deg, int* __restrict__ rowptr) {
    const int NT = 1024;
    const int CH = (N_NODES + NT - 1) / NT;  // 20
    __shared__ int sums[NT];
    int t = threadIdx.x;
    int base = t * CH;
    int s = 0;
    for (int i = 0; i < CH; ++i) {
        int idx = base + i;
        if (idx < N_NODES) s += deg[idx];
    }
    sums[t] = s;
    __syncthreads();
    for (int off = 1; off < NT; off <<= 1) {
        int v = (t >= off) ? sums[t - off] : 0;
        __syncthreads();
        sums[t] += v;
        __syncthreads();
    }
    int run = (t > 0) ? sums[t - 1] : 0;
    for (int i = 0; i < CH; ++i) {
        int idx = base + i;
        if (idx < N_NODES) {
            rowptr[idx] = run;
            run += deg[idx];
        }
    }
    if (t == NT - 1) rowptr[N_NODES] = sums[NT - 1];
}

__global__ void fill_kernel(const int* __restrict__ ei, const int* __restrict__ rowptr,
                            int* __restrict__ cursor, int* __restrict__ eidx) {
    int e = blockIdx.x * blockDim.x + threadIdx.x;
    if (e < N_EDGES) {
        int dst = ei[N_EDGES + e];
        int p = rowptr[dst] + atomicAdd(&cursor[dst], 1);
        eidx[p] = e;
    }
}

// ---------------------------------------------------------------------------
// Y[n, dout] = X[n, DIN] @ W[dout, DIN]^T + b    (dout multiple of 64)
// block = 256 threads, 16 nodes per block; each thread does 4 outs per chunk
// ---------------------------------------------------------------------------
template <int DIN>
__global__ void linear_kernel(const float* __restrict__ X, const float* __restrict__ W,
                              const float* __restrict__ b, float* __restrict__ Y, int dout) {
    __shared__ float xs[16][DIN + 1];
    int tid = threadIdx.x;
    int nb = blockIdx.x * 16;
    for (int i = tid; i < 16 * DIN; i += 256) {
        int r = i / DIN, c = i % DIN;
        int node = nb + r;
        xs[r][c] = (node < N_NODES) ? X[(size_t)node * DIN + c] : 0.f;
    }
    __syncthreads();
    int ln = tid & 15, og = tid >> 4;
    int node = nb + ln;
    if (node >= N_NODES) return;
    int nchunk = dout >> 6;
    for (int m = 0; m < nchunk; ++m) {
        int o0 = m * 64 + og;
        const float* w0 = W + (size_t)(o0)      * DIN;
        const float* w1 = W + (size_t)(o0 + 16) * DIN;
        const float* w2 = W + (size_t)(o0 + 32) * DIN;
        const float* w3 = W + (size_t)(o0 + 48) * DIN;
        float a0 = 0.f, a1 = 0.f, a2 = 0.f, a3 = 0.f;
        #pragma unroll 8
        for (int k = 0; k < DIN; ++k) {
            float xv = xs[ln][k];
            a0 += xv * w0[k];
            a1 += xv * w1[k];
            a2 += xv * w2[k];
            a3 += xv * w3[k];
        }
        size_t yb = (size_t)node * dout + o0;
        Y[yb]      = a0 + b[o0];
        Y[yb + 16] = a1 + b[o0 + 16];
        Y[yb + 32] = a2 + b[o0 + 32];
        Y[yb + 48] = a3 + b[o0 + 48];
    }
}

// ---------------------------------------------------------------------------
// P1[n, h*32+d] = sum_c q1[n, h*128+c] * We1[(h*128+c)*32 + d]
// ---------------------------------------------------------------------------
__global__ void p1_kernel(const float* __restrict__ q1, const float* __restrict__ We1,
                          float* __restrict__ P1) {
    __shared__ float qs[8][D1 + 1];
    int tid = threadIdx.x;
    int nb = blockIdx.x * 8;
    for (int i = tid; i < 8 * D1; i += 256) {
        int r = i >> 9, c = i & 511;
        int node = nb + r;
        qs[r][c] = (node < N_NODES) ? q1[(size_t)node * D1 + c] : 0.f;
    }
    __syncthreads();
    int j = tid >> 5, d = tid & 31;
    int node = nb + j;
    if (node >= N_NODES) return;
    float acc[4] = {0.f, 0.f, 0.f, 0.f};
    for (int c = 0; c < 128; ++c) {
        #pragma unroll
        for (int h = 0; h < 4; ++h)
            acc[h] += qs[j][h * 128 + c] * We1[(size_t)(h * 128 + c) * 32 + d];
    }
    #pragma unroll
    for (int h = 0; h < 4; ++h) P1[(size_t)node * 128 + h * 32 + d] = acc[h];
}

// P2[n, d] = sum_c q2[n, c] * We2[c*32 + d]
__global__ void p2_kernel(const float* __restrict__ q2, const float* __restrict__ We2,
                          float* __restrict__ P2) {
    __shared__ float qs[8][D2 + 1];
    int tid = threadIdx.x;
    int nb = blockIdx.x * 8;
    for (int i = tid; i < 8 * D2; i += 256) {
        int r = i >> 6, c = i & 63;
        int node = nb + r;
        qs[r][c] = (node < N_NODES) ? q2[(size_t)node * D2 + c] : 0.f;
    }
    __syncthreads();
    int j = tid >> 5, d = tid & 31;
    int node = nb + j;
    if (node >= N_NODES) return;
    float acc = 0.f;
    #pragma unroll 8
    for (int c = 0; c < 64; ++c) acc += qs[j][c] * We2[c * 32 + d];
    P2[(size_t)node * 32 + d] = acc;
}

// ---------------------------------------------------------------------------
// Layer-1 attention: one wave per dst. lane owns channels c0..c0+7 (c0=lane*8)
// head = lane/16; softmax reduce within 16-lane group.
// hbuf holds skip (s1) on input; holds relu(out + skip) on output.
// ---------------------------------------------------------------------------
__global__ void attn1_kernel(const float* __restrict__ q1, const float* __restrict__ k1,
                             const float* __restrict__ v1, const float* __restrict__ P1,
                             const float* __restrict__ ea, const int* __restrict__ ei,
                             const int* __restrict__ rowptr, const int* __restrict__ eidx,
                             const float* __restrict__ We1, float* __restrict__ hbuf) {
    int wid = threadIdx.x >> 6, lane = threadIdx.x & 63;
    int dst = blockIdx.x * 4 + wid;
    if (dst >= N_NODES) return;
    int c0 = lane * 8;
    int hh = lane >> 4;
    int d0 = (lane & 15) * 2;
    const float4* qp = (const float4*)(q1 + (size_t)dst * D1 + c0);
    float4 qa = qp[0], qb = qp[1];
    float pA = P1[(size_t)dst * 128 + hh * 32 + d0];
    float pB = P1[(size_t)dst * 128 + hh * 32 + d0 + 1];
    float acc[8] = {0.f, 0.f, 0.f, 0.f, 0.f, 0.f, 0.f, 0.f};
    float t0 = 0.f, t1 = 0.f, denom = 0.f;
    int beg = rowptr[dst], end = rowptr[dst + 1];
    for (int i = beg; i < end; ++i) {
        int e = eidx[i];
        int src = ei[e];
        const float4* kp = (const float4*)(k1 + (size_t)src * D1 + c0);
        float4 ka = kp[0], kb = kp[1];
        const float4* vp = (const float4*)(v1 + (size_t)src * D1 + c0);
        float4 va = vp[0], vb = vp[1];
        float ea0 = ea[(size_t)e * 32 + d0];
        float ea1 = ea[(size_t)e * 32 + d0 + 1];
        float s = qa.x * ka.x + qa.y * ka.y + qa.z * ka.z + qa.w * ka.w
                + qb.x * kb.x + qb.y * kb.y + qb.z * kb.z + qb.w * kb.w
                + pA * ea0 + pB * ea1;
        s += __shfl_xor(s, 1);
        s += __shfl_xor(s, 2);
        s += __shfl_xor(s, 4);
        s += __shfl_xor(s, 8);
        float wgt = __expf(s * 0.08838834764831845f);  // 1/sqrt(128)
        denom += wgt;
        acc[0] += wgt * va.x; acc[1] += wgt * va.y;
        acc[2] += wgt * va.z; acc[3] += wgt * va.w;
        acc[4] += wgt * vb.x; acc[5] += wgt * vb.y;
        acc[6] += wgt * vb.z; acc[7] += wgt * vb.w;
        t0 += wgt * ea0;
        t1 += wgt * ea1;
    }
    // gather this head's t[h, 0..31] from the 16-lane group
    float tt[32];
    int gbase = lane & 48;
    #pragma unroll
    for (int d = 0; d < 32; ++d)
        tt[d] = __shfl((d & 1) ? t1 : t0, gbase + (d >> 1));
    float inv = (end > beg) ? 1.f / denom : 0.f;
    float* hp = hbuf + (size_t)dst * D1 + c0;
    #pragma unroll
    for (int j = 0; j < 8; ++j) {
        const float4* wr = (const float4*)(We1 + (size_t)(c0 + j) * 32);
        float sum = 0.f;
        #pragma unroll
        for (int d4 = 0; d4 < 8; ++d4) {
            float4 w4 = wr[d4];
            sum += w4.x * tt[d4 * 4] + w4.y * tt[d4 * 4 + 1]
                 + w4.z * tt[d4 * 4 + 2] + w4.w * tt[d4 * 4 + 3];
        }
        float v = (acc[j] + sum) * inv + hp[j];  // + skip
        hp[j] = v > 0.f ? v : 0.f;               // relu
    }
}

// ---------------------------------------------------------------------------
// Layer-2 attention: one wave per dst, 1 head, C=64 -> lane owns channel=lane
// ---------------------------------------------------------------------------
__global__ void attn2_kernel(const float* __restrict__ q2, const float* __restrict__ k2,
                             const float* __restrict__ v2, const float* __restrict__ P2,
                             const float* __restrict__ ea, const int* __restrict__ ei,
                             const int* __restrict__ rowptr, const int* __restrict__ eidx,
                             const float* __restrict__ We2, const float* __restrict__ s2,
                             float* __restrict__ zout) {
    int wid = threadIdx.x >> 6, lane = threadIdx.x & 63;
    int dst = blockIdx.x * 4 + wid;
    if (dst >= N_NODES) return;
    float qv = q2[(size_t)dst * D2 + lane];
    float pv = (lane < 32) ? P2[(size_t)dst * 32 + lane] : 0.f;
    float acc = 0.f, t = 0.f, denom = 0.f;
    int beg = rowptr[dst], end = rowptr[dst + 1];
    for (int i = beg; i < end; ++i) {
        int e = eidx[i];
        int src = ei[e];
        float kv = k2[(size_t)src * D2 + lane];
        float vv = v2[(size_t)src * D2 + lane];
        float eav = (lane < 32) ? ea[(size_t)e * 32 + lane] : 0.f;
        float s = qv * kv + pv * eav;
        s += __shfl_xor(s, 1);
        s += __shfl_xor(s, 2);
        s += __shfl_xor(s, 4);
        s += __shfl_xor(s, 8);
        s += __shfl_xor(s, 16);
        s += __shfl_xor(s, 32);
        float wgt = __expf(s * 0.125f);  // 1/sqrt(64)
        denom += wgt;
        acc += wgt * vv;
        t += wgt * eav;
    }
    float tt[32];
    #pragma unroll
    for (int d = 0; d < 32; ++d) tt[d] = __shfl(t, d);
    float inv = (end > beg) ? 1.f / denom : 0.f;
    const float4* wr = (const float4*)(We2 + (size_t)lane * 32);
    float sum = 0.f;
    #pragma unroll
    for (int d4 = 0; d4 < 8; ++d4) {
        float4 w4 = wr[d4];
        sum += w4.x * tt[d4 * 4] + w4.y * tt[d4 * 4 + 1]
             + w4.z * tt[d4 * 4 + 2] + w4.w * tt[d4 * 4 + 3];
    }
    zout[(size_t)dst * D2 + lane] = (acc + sum) * inv + s2[(size_t)dst * D2 + lane];
}

// ---------------------------------------------------------------------------
extern "C" void kernel_launch(void* const* d_in, const int* in_sizes, int n_in,
                              void* d_out, int out_size, void* d_ws, size_t ws_size,
                              hipStream_t stream) {
    const float* x   = (const float*)d_in[0];
    const int*   ei  = (const int*)d_in[1];
    const float* ea  = (const float*)d_in[2];
    const float* Wq1 = (const float*)d_in[3];  const float* bq1 = (const float*)d_in[4];
    const float* Wk1 = (const float*)d_in[5];  const float* bk1 = (const float*)d_in[6];
    const float* Wv1 = (const float*)d_in[7];  const float* bv1 = (const float*)d_in[8];
    const float* We1 = (const float*)d_in[9];
    const float* Ws1 = (const float*)d_in[10]; const float* bs1 = (const float*)d_in[11];
    const float* Wq2 = (const float*)d_in[12]; const float* bq2 = (const float*)d_in[13];
    const float* Wk2 = (const float*)d_in[14]; const float* bk2 = (const float*)d_in[15];
    const float* Wv2 = (const float*)d_in[16]; const float* bv2 = (const float*)d_in[17];
    const float* We2 = (const float*)d_in[18];
    const float* Ws2 = (const float*)d_in[19]; const float* bs2 = (const float*)d_in[20];
    float* zout = (float*)d_out;

    char* wsb = (char*)d_ws;
    size_t off = 0;
    auto alloc = [&](size_t bytes) -> void* {
        void* p = wsb + off;
        off += (bytes + 255) & ~(size_t)255;
        return p;
    };
    float* q1 = (float*)alloc((size_t)N_NODES * D1 * 4);
    float* k1 = (float*)alloc((size_t)N_NODES * D1 * 4);
    float* v1 = (float*)alloc((size_t)N_NODES * D1 * 4);
    float* hb = (float*)alloc((size_t)N_NODES * D1 * 4);  // s1, then h
    float* P1 = (float*)alloc((size_t)N_NODES * 128 * 4);
    int* deg    = (int*)alloc((size_t)N_NODES * 4);
    int* cursor = (int*)alloc((size_t)N_NODES * 4);
    int* rowptr = (int*)alloc((size_t)(N_NODES + 1) * 4);
    int* eidx   = (int*)alloc((size_t)N_EDGES * 4);
    // layer-2 buffers alias q1 (dead after attn1): 4*64 + 32 = 288 <= 512 cols
    float* q2 = q1;
    float* k2 = q1 + (size_t)1 * N_NODES * D2;
    float* v2 = q1 + (size_t)2 * N_NODES * D2;
    float* s2 = q1 + (size_t)3 * N_NODES * D2;
    float* P2 = q1 + (size_t)4 * N_NODES * D2;

    hipMemsetAsync(deg, 0, (size_t)N_NODES * 4, stream);
    hipMemsetAsync(cursor, 0, (size_t)N_NODES * 4, stream);

    hist_kernel<<<(N_EDGES + 255) / 256, 256, 0, stream>>>(ei, deg);
    scan_kernel<<<1, 1024, 0, stream>>>(deg, rowptr);
    fill_kernel<<<(N_EDGES + 255) / 256, 256, 0, stream>>>(ei, rowptr, cursor, eidx);

    int nb16 = (N_NODES + 15) / 16;
    linear_kernel<128><<<nb16, 256, 0, stream>>>(x, Wq1, bq1, q1, D1);
    linear_kernel<128><<<nb16, 256, 0, stream>>>(x, Wk1, bk1, k1, D1);
    linear_kernel<128><<<nb16, 256, 0, stream>>>(x, Wv1, bv1, v1, D1);
    linear_kernel<128><<<nb16, 256, 0, stream>>>(x, Ws1, bs1, hb, D1);
    p1_kernel<<<(N_NODES + 7) / 8, 256, 0, stream>>>(q1, We1, P1);
    attn1_kernel<<<(N_NODES + 3) / 4, 256, 0, stream>>>(q1, k1, v1, P1, ea, ei,
                                                        rowptr, eidx, We1, hb);

    linear_kernel<512><<<nb16, 256, 0, stream>>>(hb, Wq2, bq2, q2, D2);
    linear_kernel<512><<<nb16, 256, 0, stream>>>(hb, Wk2, bk2, k2, D2);
    linear_kernel<512><<<nb16, 256, 0, stream>>>(hb, Wv2, bv2, v2, D2);
    linear_kernel<512><<<nb16, 256, 0, stream>>>(hb, Ws2, bs2, s2, D2);
    p2_kernel<<<(N_NODES + 7) / 8, 256, 0, stream>>>(q2, We2, P2);
    attn2_kernel<<<(N_NODES + 3) / 4, 256, 0, stream>>>(q2, k2, v2, P2, ea, ei,
                                                        rowptr, eidx, We2, s2, zout);
}

// Round 2
// 549.693 us; speedup vs baseline: 2.9511x; 2.9511x over previous
//
#include <hip/hip_runtime.h>
#include <hip/hip_bf16.h>
#include <math.h>

#define N_NODES 20000
#define N_EDGES 160000
#define D1 512    // layer-1 width: 4 heads * 128
#define D2 64     // layer-2 width: 1 head * 64
#define Y1W 2176  // q(0) k(512) v(1024) s(1536) P1(2048..2175)
#define Y2W 288   // q(0) k(64) v(128) s(192) P2(256..287)

typedef __attribute__((ext_vector_type(8))) short short8;
typedef __attribute__((ext_vector_type(4))) float floatx4;

__device__ __forceinline__ float bf2f(short u) {
    return __uint_as_float(((unsigned)(unsigned short)u) << 16);
}
__device__ __forceinline__ short f2bf(float f) {
    __hip_bfloat16 h = __float2bfloat16(f);
    return *(short*)&h;
}

// ---------------------------------------------------------------------------
// CSR build (by dst); fill stores (src, edge_id) pairs to kill one load level
// ---------------------------------------------------------------------------
__global__ void hist_kernel(const int* __restrict__ ei, int* __restrict__ deg) {
    int e = blockIdx.x * blockDim.x + threadIdx.x;
    if (e < N_EDGES) atomicAdd(&deg[ei[N_EDGES + e]], 1);
}

__global__ void scan_kernel(const int* __restrict__ deg, int* __restrict__ rowptr) {
    const int NT = 1024;
    const int CH = (N_NODES + NT - 1) / NT;
    __shared__ int sums[NT];
    int t = threadIdx.x;
    int base = t * CH;
    int s = 0;
    for (int i = 0; i < CH; ++i) {
        int idx = base + i;
        if (idx < N_NODES) s += deg[idx];
    }
    sums[t] = s;
    __syncthreads();
    for (int off = 1; off < NT; off <<= 1) {
        int v = (t >= off) ? sums[t - off] : 0;
        __syncthreads();
        sums[t] += v;
        __syncthreads();
    }
    int run = (t > 0) ? sums[t - 1] : 0;
    for (int i = 0; i < CH; ++i) {
        int idx = base + i;
        if (idx < N_NODES) {
            rowptr[idx] = run;
            run += deg[idx];
        }
    }
    if (t == NT - 1) rowptr[N_NODES] = sums[NT - 1];
}

__global__ void fill_kernel(const int* __restrict__ ei, const int* __restrict__ rowptr,
                            int* __restrict__ cursor, int2* __restrict__ e2) {
    int e = blockIdx.x * blockDim.x + threadIdx.x;
    if (e < N_EDGES) {
        int src = ei[e];
        int dst = ei[N_EDGES + e];
        int p = rowptr[dst] + atomicAdd(&cursor[dst], 1);
        e2[p] = make_int2(src, e);
    }
}

// ---------------------------------------------------------------------------
// Weight prep: concatenated bf16 weights + fp32 bias, P-columns folded in.
// W1b[2176][128]: rows 0..2047 = [Wq1;Wk1;Wv1;Ws1]; rows 2048+h*32+d =
//   M1 row: M1[k] = sum_c Wq1[h*128+c][k] * We1[(h*128+c)][d]
// ---------------------------------------------------------------------------
__global__ void prep1_kernel(const float* __restrict__ Wq1, const float* __restrict__ bq1,
                             const float* __restrict__ Wk1, const float* __restrict__ bk1,
                             const float* __restrict__ Wv1, const float* __restrict__ bv1,
                             const float* __restrict__ Ws1, const float* __restrict__ bs1,
                             const float* __restrict__ We1,
                             __hip_bfloat16* __restrict__ W1b, float* __restrict__ b1) {
    int j = blockIdx.x, t = threadIdx.x;  // t = k in [0,128)
    if (j < 2048) {
        int sel = j >> 9, r = j & 511;
        const float* W = sel == 0 ? Wq1 : sel == 1 ? Wk1 : sel == 2 ? Wv1 : Ws1;
        const float* bs = sel == 0 ? bq1 : sel == 1 ? bk1 : sel == 2 ? bv1 : bs1;
        W1b[(size_t)j * 128 + t] = __float2bfloat16(W[(size_t)r * 128 + t]);
        if (t == 0) b1[j] = bs[r];
    } else {
        int hd = j - 2048, h = hd >> 5, d = hd & 31;
        float acc = 0.f;
        for (int c = 0; c < 128; ++c)
            acc += Wq1[(size_t)(h * 128 + c) * 128 + t] * We1[(size_t)(h * 128 + c) * 32 + d];
        W1b[(size_t)j * 128 + t] = __float2bfloat16(acc);
        if (t == 0) {
            float b = 0.f;
            for (int c = 0; c < 128; ++c) b += bq1[h * 128 + c] * We1[(size_t)(h * 128 + c) * 32 + d];
            b1[j] = b;
        }
    }
}

// W2b[288][512]: rows 0..255 = [Wq2;Wk2;Wv2;Ws2]; rows 256+d = M2 row
__global__ void prep2_kernel(const float* __restrict__ Wq2, const float* __restrict__ bq2,
                             const float* __restrict__ Wk2, const float* __restrict__ bk2,
                             const float* __restrict__ Wv2, const float* __restrict__ bv2,
                             const float* __restrict__ Ws2, const float* __restrict__ bs2,
                             const float* __restrict__ We2,
                             __hip_bfloat16* __restrict__ W2b, float* __restrict__ b2) {
    int j = blockIdx.x, t = threadIdx.x;
    for (int kk = t; kk < 512; kk += 256) {
        float val;
        if (j < 256) {
            int sel = j >> 6, r = j & 63;
            const float* W = sel == 0 ? Wq2 : sel == 1 ? Wk2 : sel == 2 ? Wv2 : Ws2;
            val = W[(size_t)r * 512 + kk];
        } else {
            int d = j - 256;
            float acc = 0.f;
            for (int c = 0; c < 64; ++c) acc += Wq2[(size_t)c * 512 + kk] * We2[c * 32 + d];
            val = acc;
        }
        W2b[(size_t)j * 512 + kk] = __float2bfloat16(val);
    }
    if (t == 0) {
        if (j < 256) {
            int sel = j >> 6, r = j & 63;
            const float* bs = sel == 0 ? bq2 : sel == 1 ? bk2 : sel == 2 ? bv2 : bs2;
            b2[j] = bs[r];
        } else {
            int d = j - 256;
            float b = 0.f;
            for (int c = 0; c < 64; ++c) b += bq2[c] * We2[c * 32 + d];
            b2[j] = b;
        }
    }
}

// ---------------------------------------------------------------------------
// MFMA GEMM: C[M,N] = A[M,K] @ B[N,K]^T + bias.  128x128 tile, 4 waves (2x2),
// each wave 64x64 via 4x4 16x16x32 bf16 fragments. Reg-staged LDS with
// k-slot XOR swizzle (kslot ^ (row&15)) -> conflict-free ds_read_b128.
// A_F32: read A as fp32 and convert (fuses the x->bf16 cast).
// ---------------------------------------------------------------------------
template <int K, bool A_F32, bool OUT_BF16>
__global__ __launch_bounds__(256) void gemm_bt(const void* __restrict__ Ap,
                                               const __hip_bfloat16* __restrict__ B,
                                               const float* __restrict__ bias,
                                               void* __restrict__ Cout,
                                               int M, int N, int tiles_n) {
    __shared__ char lds[65536];
    char* ldsA = lds;
    char* ldsB = lds + 32768;
    int tid = threadIdx.x;
    int bm = blockIdx.x / tiles_n, bn = blockIdx.x % tiles_n;
    int w = tid >> 6, lane = tid & 63;
    int wr = (w >> 1) * 64, wc = (w & 1) * 64;
    int lrow = lane & 15, lk = lane >> 4;
    floatx4 acc[4][4] = {};

    for (int kt = 0; kt < K / 128; ++kt) {
        if (kt) __syncthreads();
        #pragma unroll
        for (int it = 0; it < 8; ++it) {
            int s = it * 256 + tid;
            int row = s >> 4, kslot = s & 15;
            int phys = ((kslot ^ (row & 15)) << 4);
            int gr = bm * 128 + row;
            if (gr > M - 1) gr = M - 1;
            short8 va;
            if (A_F32) {
                const float* Af = (const float*)Ap;
                float4 x0 = *(const float4*)(Af + (size_t)gr * K + kt * 128 + kslot * 8);
                float4 x1 = *(const float4*)(Af + (size_t)gr * K + kt * 128 + kslot * 8 + 4);
                va[0] = f2bf(x0.x); va[1] = f2bf(x0.y); va[2] = f2bf(x0.z); va[3] = f2bf(x0.w);
                va[4] = f2bf(x1.x); va[5] = f2bf(x1.y); va[6] = f2bf(x1.z); va[7] = f2bf(x1.w);
            } else {
                const __hip_bfloat16* Ab = (const __hip_bfloat16*)Ap;
                va = *(const short8*)(Ab + (size_t)gr * K + kt * 128 + kslot * 8);
            }
            *(short8*)(ldsA + row * 256 + phys) = va;
            int gc = bn * 128 + row;
            if (gc > N - 1) gc = N - 1;
            short8 vb = *(const short8*)(B + (size_t)gc * K + kt * 128 + kslot * 8);
            *(short8*)(ldsB + row * 256 + phys) = vb;
        }
        __syncthreads();
        #pragma unroll
        for (int ks = 0; ks < 4; ++ks) {
            short8 af[4], bfr[4];
            #pragma unroll
            for (int m = 0; m < 4; ++m) {
                int r = wr + m * 16 + lrow;
                int kslot = ks * 4 + lk;
                af[m] = *(const short8*)(ldsA + r * 256 + ((kslot ^ (r & 15)) << 4));
            }
            #pragma unroll
            for (int n = 0; n < 4; ++n) {
                int c = wc + n * 16 + lrow;
                int kslot = ks * 4 + lk;
                bfr[n] = *(const short8*)(ldsB + c * 256 + ((kslot ^ (c & 15)) << 4));
            }
            #pragma unroll
            for (int m = 0; m < 4; ++m)
                #pragma unroll
                for (int n = 0; n < 4; ++n)
                    acc[m][n] = __builtin_amdgcn_mfma_f32_16x16x32_bf16(af[m], bfr[n], acc[m][n], 0, 0, 0);
        }
    }

    #pragma unroll
    for (int m = 0; m < 4; ++m) {
        #pragma unroll
        for (int j = 0; j < 4; ++j) {
            int r = bm * 128 + wr + m * 16 + lk * 4 + j;
            if (r >= M) continue;
            #pragma unroll
            for (int n = 0; n < 4; ++n) {
                int gc = bn * 128 + wc + n * 16 + lrow;
                if (gc >= N) continue;
                float v = acc[m][n][j] + bias[gc];
                if (OUT_BF16)
                    ((__hip_bfloat16*)Cout)[(size_t)r * N + gc] = __float2bfloat16(v);
                else
                    ((float*)Cout)[(size_t)r * N + gc] = v;
            }
        }
    }
}

// ---------------------------------------------------------------------------
// Layer-1 attention: one wave per dst; lane owns 8 channels (c0 = lane*8),
// head = lane/16; 16-lane-group softmax reduce; edge loop unrolled x2.
// Reads bf16 Y1 (stride 2176), writes bf16 h (= relu(out + skip)).
// ---------------------------------------------------------------------------
__global__ __launch_bounds__(256) void attn1_kernel(
    const __hip_bfloat16* __restrict__ Y1, const float* __restrict__ ea,
    const int2* __restrict__ e2, const int* __restrict__ rowptr,
    const float* __restrict__ We1, __hip_bfloat16* __restrict__ hb) {
    int wid = threadIdx.x >> 6, lane = threadIdx.x & 63;
    int dst = blockIdx.x * 4 + wid;
    if (dst >= N_NODES) return;
    int c0 = lane * 8;
    int hh = lane >> 4;
    int d0 = (lane & 15) * 2;
    const size_t rowb = (size_t)dst * Y1W;
    short8 qv = *(const short8*)(Y1 + rowb + c0);
    float q[8];
    #pragma unroll
    for (int j = 0; j < 8; ++j) q[j] = bf2f(qv[j]);
    const __hip_bfloat16* pp = Y1 + rowb + 2048 + hh * 32 + d0;
    float pA = __bfloat162float(pp[0]);
    float pB = __bfloat162float(pp[1]);

    float acc[8] = {0.f, 0.f, 0.f, 0.f, 0.f, 0.f, 0.f, 0.f};
    float t0 = 0.f, t1 = 0.f, denom = 0.f;
    int beg = rowptr[dst], end = rowptr[dst + 1];

    auto proc = [&](short8 kv, short8 vv, float ea0, float ea1) {
        float s = pA * ea0 + pB * ea1;
        #pragma unroll
        for (int j = 0; j < 8; ++j) s += q[j] * bf2f(kv[j]);
        s += __shfl_xor(s, 1);
        s += __shfl_xor(s, 2);
        s += __shfl_xor(s, 4);
        s += __shfl_xor(s, 8);
        float wgt = __expf(s * 0.08838834764831845f);  // 1/sqrt(128)
        denom += wgt;
        #pragma unroll
        for (int j = 0; j < 8; ++j) acc[j] += wgt * bf2f(vv[j]);
        t0 += wgt * ea0;
        t1 += wgt * ea1;
    };

    int i = beg;
    for (; i + 2 <= end; i += 2) {
        int2 eA = e2[i], eB = e2[i + 1];
        const size_t ra = (size_t)eA.x * Y1W, rb = (size_t)eB.x * Y1W;
        short8 kA = *(const short8*)(Y1 + ra + 512 + c0);
        short8 kB = *(const short8*)(Y1 + rb + 512 + c0);
        short8 vA = *(const short8*)(Y1 + ra + 1024 + c0);
        short8 vB = *(const short8*)(Y1 + rb + 1024 + c0);
        float2 fA = *(const float2*)(ea + (size_t)eA.y * 32 + d0);
        float2 fB = *(const float2*)(ea + (size_t)eB.y * 32 + d0);
        proc(kA, vA, fA.x, fA.y);
        proc(kB, vB, fB.x, fB.y);
    }
    if (i < end) {
        int2 eA = e2[i];
        const size_t ra = (size_t)eA.x * Y1W;
        short8 kA = *(const short8*)(Y1 + ra + 512 + c0);
        short8 vA = *(const short8*)(Y1 + ra + 1024 + c0);
        float2 fA = *(const float2*)(ea + (size_t)eA.y * 32 + d0);
        proc(kA, vA, fA.x, fA.y);
    }

    // gather this head's t[0..31] from the 16-lane group
    float tt[32];
    int gbase = lane & 48;
    #pragma unroll
    for (int d = 0; d < 32; ++d)
        tt[d] = __shfl((d & 1) ? t1 : t0, gbase + (d >> 1));
    float inv = (end > beg) ? 1.f / denom : 0.f;
    short8 sv = *(const short8*)(Y1 + rowb + 1536 + c0);
    short8 hv;
    #pragma unroll
    for (int j = 0; j < 8; ++j) {
        const float4* wr = (const float4*)(We1 + (size_t)(c0 + j) * 32);
        float sum = 0.f;
        #pragma unroll
        for (int d4 = 0; d4 < 8; ++d4) {
            float4 w4 = wr[d4];
            sum += w4.x * tt[d4 * 4] + w4.y * tt[d4 * 4 + 1]
                 + w4.z * tt[d4 * 4 + 2] + w4.w * tt[d4 * 4 + 3];
        }
        float v = (acc[j] + sum) * inv + bf2f(sv[j]);
        hv[j] = f2bf(v > 0.f ? v : 0.f);
    }
    *(short8*)(hb + (size_t)dst * D1 + c0) = hv;
}

// ---------------------------------------------------------------------------
// Layer-2 attention: one wave per dst, 1 head, C=64 -> lane owns one channel.
// Reads fp32 Y2 (stride 288), writes fp32 zout.
// ---------------------------------------------------------------------------
__global__ __launch_bounds__(256) void attn2_kernel(
    const float* __restrict__ Y2, const float* __restrict__ ea,
    const int2* __restrict__ e2, const int* __restrict__ rowptr,
    const float* __restrict__ We2, float* __restrict__ zout) {
    int wid = threadIdx.x >> 6, lane = threadIdx.x & 63;
    int dst = blockIdx.x * 4 + wid;
    if (dst >= N_NODES) return;
    const size_t rowb = (size_t)dst * Y2W;
    float qv = Y2[rowb + lane];
    float pv = (lane < 32) ? Y2[rowb + 256 + lane] : 0.f;
    float acc = 0.f, t = 0.f, denom = 0.f;
    int beg = rowptr[dst], end = rowptr[dst + 1];

    auto proc = [&](float kv, float vv, float eav) {
        float s = qv * kv + pv * eav;
        s += __shfl_xor(s, 1);
        s += __shfl_xor(s, 2);
        s += __shfl_xor(s, 4);
        s += __shfl_xor(s, 8);
        s += __shfl_xor(s, 16);
        s += __shfl_xor(s, 32);
        float wgt = __expf(s * 0.125f);  // 1/sqrt(64)
        denom += wgt;
        acc += wgt * vv;
        t += wgt * eav;
    };

    int i = beg;
    for (; i + 2 <= end; i += 2) {
        int2 eA = e2[i], eB = e2[i + 1];
        const size_t ra = (size_t)eA.x * Y2W, rb = (size_t)eB.x * Y2W;
        float kA = Y2[ra + 64 + lane], kB = Y2[rb + 64 + lane];
        float vA = Y2[ra + 128 + lane], vB = Y2[rb + 128 + lane];
        float eaA = (lane < 32) ? ea[(size_t)eA.y * 32 + lane] : 0.f;
        float eaB = (lane < 32) ? ea[(size_t)eB.y * 32 + lane] : 0.f;
        proc(kA, vA, eaA);
        proc(kB, vB, eaB);
    }
    if (i < end) {
        int2 eA = e2[i];
        const size_t ra = (size_t)eA.x * Y2W;
        proc(Y2[ra + 64 + lane], Y2[ra + 128 + lane],
             (lane < 32) ? ea[(size_t)eA.y * 32 + lane] : 0.f);
    }

    float tt[32];
    #pragma unroll
    for (int d = 0; d < 32; ++d) tt[d] = __shfl(t, d);
    float inv = (end > beg) ? 1.f / denom : 0.f;
    const float4* wr = (const float4*)(We2 + (size_t)lane * 32);
    float sum = 0.f;
    #pragma unroll
    for (int d4 = 0; d4 < 8; ++d4) {
        float4 w4 = wr[d4];
        sum += w4.x * tt[d4 * 4] + w4.y * tt[d4 * 4 + 1]
             + w4.z * tt[d4 * 4 + 2] + w4.w * tt[d4 * 4 + 3];
    }
    zout[(size_t)dst * D2 + lane] = (acc + sum) * inv + Y2[rowb + 192 + lane];
}

// ---------------------------------------------------------------------------
extern "C" void kernel_launch(void* const* d_in, const int* in_sizes, int n_in,
                              void* d_out, int out_size, void* d_ws, size_t ws_size,
                              hipStream_t stream) {
    const float* x   = (const float*)d_in[0];
    const int*   ei  = (const int*)d_in[1];
    const float* ea  = (const float*)d_in[2];
    const float* Wq1 = (const float*)d_in[3];  const float* bq1 = (const float*)d_in[4];
    const float* Wk1 = (const float*)d_in[5];  const float* bk1 = (const float*)d_in[6];
    const float* Wv1 = (const float*)d_in[7];  const float* bv1 = (const float*)d_in[8];
    const float* We1 = (const float*)d_in[9];
    const float* Ws1 = (const float*)d_in[10]; const float* bs1 = (const float*)d_in[11];
    const float* Wq2 = (const float*)d_in[12]; const float* bq2 = (const float*)d_in[13];
    const float* Wk2 = (const float*)d_in[14]; const float* bk2 = (const float*)d_in[15];
    const float* Wv2 = (const float*)d_in[16]; const float* bv2 = (const float*)d_in[17];
    const float* We2 = (const float*)d_in[18];
    const float* Ws2 = (const float*)d_in[19]; const float* bs2 = (const float*)d_in[20];
    float* zout = (float*)d_out;

    char* wsb = (char*)d_ws;
    size_t off = 0;
    auto alloc = [&](size_t bytes) -> void* {
        void* p = wsb + off;
        off += (bytes + 255) & ~(size_t)255;
        return p;
    };
    __hip_bfloat16* Y1  = (__hip_bfloat16*)alloc((size_t)N_NODES * Y1W * 2);
    __hip_bfloat16* hbb = (__hip_bfloat16*)alloc((size_t)N_NODES * D1 * 2);
    float*          Y2  = (float*)alloc((size_t)N_NODES * Y2W * 4);
    __hip_bfloat16* W1b = (__hip_bfloat16*)alloc((size_t)2176 * 128 * 2);
    float*          b1  = (float*)alloc(2176 * 4);
    __hip_bfloat16* W2b = (__hip_bfloat16*)alloc((size_t)288 * 512 * 2);
    float*          b2  = (float*)alloc(288 * 4);
    int* deg    = (int*)alloc((size_t)N_NODES * 4);
    int* cursor = (int*)alloc((size_t)N_NODES * 4);
    int* rowptr = (int*)alloc((size_t)(N_NODES + 1) * 4);
    int2* e2    = (int2*)alloc((size_t)N_EDGES * 8);

    hipMemsetAsync(deg, 0, (size_t)N_NODES * 4, stream);
    hipMemsetAsync(cursor, 0, (size_t)N_NODES * 4, stream);

    // CSR build
    hist_kernel<<<(N_EDGES + 255) / 256, 256, 0, stream>>>(ei, deg);
    scan_kernel<<<1, 1024, 0, stream>>>(deg, rowptr);
    fill_kernel<<<(N_EDGES + 255) / 256, 256, 0, stream>>>(ei, rowptr, cursor, e2);

    // weight prep (P-columns folded in)
    prep1_kernel<<<2176, 128, 0, stream>>>(Wq1, bq1, Wk1, bk1, Wv1, bv1, Ws1, bs1,
                                           We1, W1b, b1);
    prep2_kernel<<<288, 256, 0, stream>>>(Wq2, bq2, Wk2, bk2, Wv2, bv2, Ws2, bs2,
                                          We2, W2b, b2);

    // layer 1: Y1 = x @ W1b^T + b1   (M=20000, N=2176, K=128)
    int tiles_m = (N_NODES + 127) / 128;  // 157
    gemm_bt<128, true, true><<<tiles_m * 17, 256, 0, stream>>>(
        (const void*)x, W1b, b1, (void*)Y1, N_NODES, Y1W, 17);
    attn1_kernel<<<(N_NODES + 3) / 4, 256, 0, stream>>>(Y1, ea, e2, rowptr, We1, hbb);

    // layer 2: Y2 = h @ W2b^T + b2   (M=20000, N=288, K=512)
    gemm_bt<512, false, false><<<tiles_m * 3, 256, 0, stream>>>(
        (const void*)hbb, W2b, b2, (void*)Y2, N_NODES, Y2W, 3);
    attn2_kernel<<<(N_NODES + 3) / 4, 256, 0, stream>>>(Y2, ea, e2, rowptr, We2, zout);
}